// Round 1
// baseline (273.785 us; speedup 1.0000x reference)
//
#include <hip/hip_runtime.h>

// Problem constants (match reference)
constexpr int N = 64, C = 256, H = 64, W = 64, P = 1024;

// One block per (n,p) point; 256 threads = 256 channels.
// pos is wave-uniform within a block -> no divergence on bounds checks.
// Writes: out[np*C + c] contiguous across threads -> fully coalesced.
// Reads: channel-strided (H*W*4 = 16KB) corner gathers; rely on L1/L2 reuse
// across the 1024 points per image (image slice = 4 MiB = one XCD L2).
__global__ __launch_bounds__(256) void progressive_sample_kernel(
    const float* __restrict__ inp,     // [N,C,H,W]
    const float* __restrict__ point,   // [N,P,2] (y,x)
    const float* __restrict__ offset,  // [N,P,2]
    float* __restrict__ out)           // [N,P,C]
{
    const int np = blockIdx.x;          // n*P + p
    const int n  = np >> 10;            // P = 1024
    const int c  = threadIdx.x;

    // pos = point + GAMMA(=1.0) * offset
    const float y = point[np * 2 + 0] + offset[np * 2 + 0];
    const float x = point[np * 2 + 1] + offset[np * 2 + 1];

    const float y0f = floorf(y), x0f = floorf(x);
    const float ly = y - y0f, lx = x - x0f;
    const float hy = 1.0f - ly, hx = 1.0f - lx;
    const int y0 = (int)y0f, x0 = (int)x0f;
    const int y1 = y0 + 1,   x1 = x0 + 1;

    // per-corner validity (zero padding outside [0,H)x[0,W))
    const bool vy0 = (unsigned)y0 < (unsigned)H;
    const bool vy1 = (unsigned)y1 < (unsigned)H;
    const bool vx0 = (unsigned)x0 < (unsigned)W;
    const bool vx1 = (unsigned)x1 < (unsigned)W;

    const int yc0 = min(max(y0, 0), H - 1);
    const int yc1 = min(max(y1, 0), H - 1);
    const int xc0 = min(max(x0, 0), W - 1);
    const int xc1 = min(max(x1, 0), W - 1);

    const float* base = inp + (size_t)(n * C + c) * (H * W);
    const float v00 = (vy0 && vx0) ? base[yc0 * W + xc0] : 0.0f;
    const float v01 = (vy0 && vx1) ? base[yc0 * W + xc1] : 0.0f;
    const float v10 = (vy1 && vx0) ? base[yc1 * W + xc0] : 0.0f;
    const float v11 = (vy1 && vx1) ? base[yc1 * W + xc1] : 0.0f;

    out[(size_t)np * C + c] = v00 * (hy * hx) + v01 * (hy * lx)
                            + v10 * (ly * hx) + v11 * (ly * lx);
}

extern "C" void kernel_launch(void* const* d_in, const int* in_sizes, int n_in,
                              void* d_out, int out_size, void* d_ws, size_t ws_size,
                              hipStream_t stream) {
    const float* inp    = (const float*)d_in[0];
    const float* point  = (const float*)d_in[1];
    const float* offset = (const float*)d_in[2];
    float* out = (float*)d_out;

    progressive_sample_kernel<<<N * P, 256, 0, stream>>>(inp, point, offset, out);
}

// Round 2
// 201.599 us; speedup vs baseline: 1.3581x; 1.3581x over previous
//
#include <hip/hip_runtime.h>

// Problem constants (match reference)
constexpr int N = 64, C = 256, H = 64, W = 64, P = 1024;

// One block per (n,p) point; 256 threads = 256 channels.
//
// XCD swizzle: MI355X dispatches block b to XCD b%8. We remap so that
// XCD x owns images {x, x+8, ..., x+56} and walks each image's 1024 points
// contiguously -> per-XCD working set at any instant is one image slice
// (C*H*W*4 = 4 MiB) = exactly one XCD's L2. Without this, all 8 XCDs
// re-fetch every image slice (measured 3.6x HBM over-fetch in round 1).
//
// Output is write-once: non-temporal stores keep the 64 MiB stream from
// evicting input tiles out of L2.
__global__ __launch_bounds__(256) void progressive_sample_kernel(
    const float* __restrict__ inp,     // [N,C,H,W]
    const float* __restrict__ point,   // [N,P,2] (y,x)
    const float* __restrict__ offset,  // [N,P,2]
    float* __restrict__ out)           // [N,P,C]
{
    // Bijective swizzle: b = x + 8*j, j = (image-within-XCD)*1024 + p
    const int b = blockIdx.x;
    const int x8 = b & 7;               // XCD id under b%8 dispatch
    const int j  = b >> 3;              // 0..8191
    const int n  = x8 + ((j >> 10) << 3);  // image: x8 + 8*(j/1024)
    const int p  = j & 1023;
    const int np = (n << 10) + p;
    const int c  = threadIdx.x;

    // pos = point + GAMMA(=1.0) * offset   (block-uniform)
    const float y = point[np * 2 + 0] + offset[np * 2 + 0];
    const float x = point[np * 2 + 1] + offset[np * 2 + 1];

    const float y0f = floorf(y), x0f = floorf(x);
    const float ly = y - y0f, lx = x - x0f;
    const float hy = 1.0f - ly, hx = 1.0f - lx;
    const int y0 = (int)y0f, x0 = (int)x0f;
    const int y1 = y0 + 1,   x1 = x0 + 1;

    // per-corner validity (zero padding outside [0,H)x[0,W))
    const bool vy0 = (unsigned)y0 < (unsigned)H;
    const bool vy1 = (unsigned)y1 < (unsigned)H;
    const bool vx0 = (unsigned)x0 < (unsigned)W;
    const bool vx1 = (unsigned)x1 < (unsigned)W;

    const int yc0 = min(max(y0, 0), H - 1);
    const int yc1 = min(max(y1, 0), H - 1);
    const int xc0 = min(max(x0, 0), W - 1);
    const int xc1 = min(max(x1, 0), W - 1);

    const float* base = inp + (size_t)(n * C + c) * (H * W);
    const float v00 = (vy0 && vx0) ? base[yc0 * W + xc0] : 0.0f;
    const float v01 = (vy0 && vx1) ? base[yc0 * W + xc1] : 0.0f;
    const float v10 = (vy1 && vx0) ? base[yc1 * W + xc0] : 0.0f;
    const float v11 = (vy1 && vx1) ? base[yc1 * W + xc1] : 0.0f;

    const float r = v00 * (hy * hx) + v01 * (hy * lx)
                  + v10 * (ly * hx) + v11 * (ly * lx);
    __builtin_nontemporal_store(r, &out[(size_t)np * C + c]);
}

extern "C" void kernel_launch(void* const* d_in, const int* in_sizes, int n_in,
                              void* d_out, int out_size, void* d_ws, size_t ws_size,
                              hipStream_t stream) {
    const float* inp    = (const float*)d_in[0];
    const float* point  = (const float*)d_in[1];
    const float* offset = (const float*)d_in[2];
    float* out = (float*)d_out;

    progressive_sample_kernel<<<N * P, 256, 0, stream>>>(inp, point, offset, out);
}

// Round 3
// 80.117 us; speedup vs baseline: 3.4173x; 2.5163x over previous
//
#include <hip/hip_runtime.h>

// Problem constants (match reference)
constexpr int N = 64, C = 256, H = 64, W = 64, P = 1024;
constexpr int PLANE = H * W;           // 4096 floats = 16 KB
constexpr int PLANE_PAD = PLANE + 4;   // +4 floats: channel c's plane starts at
                                       // bank (4c)%32 -> the 8 lanes sharing a
                                       // point (distinct c, same x) hit 8
                                       // distinct LDS banks. 4100*4B stays
                                       // 16B-aligned for float4 staging.
constexpr int CG = 8;                  // channels per block
constexpr int THREADS = 512;           // 8 waves

// Block = (image n, channel-group cg of 8 channels).
//   Phase 1: stage the 8 contiguous NCHW planes (128 KB) into LDS via
//            coalesced float4 loads; pre-add point+offset into an LDS coord
//            table (8 KB).
//   Phase 2: thread t -> (point-lane pl = t>>3, channel c = t&7); 16 passes
//            cover all 1024 points. Corner gathers hit LDS (cheap random
//            access) instead of 16KB-strided global (round-2 bottleneck:
//            4B/64-lane uncoalesced gathers at 12% HBM util).
// Input is read exactly once, fully coalesced. Output: per-wave 8 points x
// 8 channels = 8x32B segments (HBM sector granule), non-temporal.
__global__ __launch_bounds__(THREADS) void progressive_sample_kernel(
    const float* __restrict__ inp,     // [N,C,H,W]
    const float* __restrict__ point,   // [N,P,2] (y,x)
    const float* __restrict__ offset,  // [N,P,2]
    float* __restrict__ out)           // [N,P,C]
{
    extern __shared__ float lds[];
    float* planes = lds;                   // [CG][PLANE_PAD]
    float* coords = lds + CG * PLANE_PAD;  // [P][2] (pos = point + offset)

    const int b  = blockIdx.x;
    const int n  = b >> 5;                 // 32 channel-groups per image
    const int cg = b & 31;
    const int t  = threadIdx.x;

    // --- stage coords: 1024 points * (y,x) = 512 float4 ---
    {
        const float4 p4 = ((const float4*)point)[((size_t)n << 9) + t];
        const float4 o4 = ((const float4*)offset)[((size_t)n << 9) + t];
        float4 r;
        r.x = p4.x + o4.x; r.y = p4.y + o4.y;
        r.z = p4.z + o4.z; r.w = p4.w + o4.w;
        ((float4*)coords)[t] = r;
    }

    // --- stage 8 planes: 128 KB contiguous in input ---
    const float4* src = (const float4*)(inp + (size_t)(n * C + cg * CG) * PLANE);
    #pragma unroll
    for (int i = 0; i < (CG * PLANE / 4) / THREADS; ++i) {   // 16 iters
        const int j  = i * THREADS + t;    // float4 index in [0, 8192)
        const int pl = j >> 10;            // plane 0..7
        const int wi = j & 1023;           // float4 within plane
        *(float4*)(planes + pl * PLANE_PAD + wi * 4) = src[j];
    }
    __syncthreads();

    // --- gather + bilinear ---
    const int c  = t & 7;
    const int pl = t >> 3;                 // 0..63
    const float* __restrict__ myplane = planes + c * PLANE_PAD;
    const size_t outbase = (((size_t)n << 10)) * C + cg * CG + c;

    #pragma unroll 4
    for (int pass = 0; pass < 16; ++pass) {
        const int p = (pass << 6) + pl;
        const float y = coords[p * 2 + 0];   // 8 lanes same addr -> broadcast
        const float x = coords[p * 2 + 1];

        const float y0f = floorf(y), x0f = floorf(x);
        const float ly = y - y0f, lx = x - x0f;
        const float hy = 1.0f - ly, hx = 1.0f - lx;
        const int y0 = (int)y0f, x0 = (int)x0f;
        const int y1 = y0 + 1,   x1 = x0 + 1;

        const bool vy0 = (unsigned)y0 < (unsigned)H;
        const bool vy1 = (unsigned)y1 < (unsigned)H;
        const bool vx0 = (unsigned)x0 < (unsigned)W;
        const bool vx1 = (unsigned)x1 < (unsigned)W;

        const int yc0 = min(max(y0, 0), H - 1);
        const int yc1 = min(max(y1, 0), H - 1);
        const int xc0 = min(max(x0, 0), W - 1);
        const int xc1 = min(max(x1, 0), W - 1);

        const float v00 = (vy0 && vx0) ? myplane[yc0 * W + xc0] : 0.0f;
        const float v01 = (vy0 && vx1) ? myplane[yc0 * W + xc1] : 0.0f;
        const float v10 = (vy1 && vx0) ? myplane[yc1 * W + xc0] : 0.0f;
        const float v11 = (vy1 && vx1) ? myplane[yc1 * W + xc1] : 0.0f;

        const float r = v00 * (hy * hx) + v01 * (hy * lx)
                      + v10 * (ly * hx) + v11 * (ly * lx);
        __builtin_nontemporal_store(r, &out[outbase + (size_t)p * C]);
    }
}

extern "C" void kernel_launch(void* const* d_in, const int* in_sizes, int n_in,
                              void* d_out, int out_size, void* d_ws, size_t ws_size,
                              hipStream_t stream) {
    const float* inp    = (const float*)d_in[0];
    const float* point  = (const float*)d_in[1];
    const float* offset = (const float*)d_in[2];
    float* out = (float*)d_out;

    const size_t shmem = (size_t)(CG * PLANE_PAD + 2 * P) * sizeof(float); // 139392 B
    hipFuncSetAttribute(reinterpret_cast<const void*>(progressive_sample_kernel),
                        hipFuncAttributeMaxDynamicSharedMemorySize, (int)shmem);
    progressive_sample_kernel<<<N * (C / CG), THREADS, shmem, stream>>>(
        inp, point, offset, out);
}